// Round 8
// baseline (141.665 us; speedup 1.0000x reference)
//
#include <hip/hip_runtime.h>

// NCC loss. Round 8: block-cooperative LDS row-ring.
// Model from R2-R7: the limiter is the L1-miss vmem path (~6.3 TB/s chip-wide
// even on L2/L3 hits). R2/R5/R6 all moved ~250 MB on it = 42-45 us. Fix:
// every global byte crosses that path ONCE per block via an LDS ring;
// vertical/horizontal reuse runs on the LDS pipe (69 TB/s) + registers.
//  - Block (256 thr, 4 waves) owns a BH=16 band: 24 rows stream through an
//    11-slot LDS ring (45 KB). 24/16 = 1.5x => ~100 MB miss-path => 16 us floor.
//  - Tick t: [write row t-1 to ring] [issue load row t (prefetch dist 2)]
//    [vertical add k=t-2 / sub k=t-11 from LDS, 2 cols/thread in registers]
//    [publish wave-edge sums] BARRIER [shuffle horizontal 9-sum + cc].
//    One barrier/tick; ring lifetime 11 makes write-after-read safe with it.
//  - Cross-wave horizontal halo: tiny parity-double-buffered LDS edge patch
//    (lanes 0,1,62,63); image edges = permanently-zero pad slots.

#define W 512
#define H 512
#define BH 16
#define NBANDS (H / BH)   // 32
#define NT 256
#define RS 11             // ring slots (minimum for 1 barrier/tick safety)

__global__ __launch_bounds__(NT)
void ncc_main(const float* __restrict__ I, const float* __restrict__ J,
              float* __restrict__ partials) {
    __shared__ float ring[RS][2][W];          // 45056 B
    __shared__ float edgebuf[2][6][4][5][3];  // [parity][wid+1(0,5=zero pad)][lane-class][q][S,v0,v1]
    __shared__ float wsum[4];

    const int tid  = threadIdx.x;
    const int lane = tid & 63;
    const int wid  = tid >> 6;

    const int b    = blockIdx.x >> 5;          // / NBANDS
    const int band = blockIdx.x & (NBANDS - 1);
    const int y0   = band * BH;

    const float* Ip = I + (size_t)b * (H * W);
    const float* Jp = J + (size_t)b * (H * W);

    // Cooperative-load role: threads 0-127 load the I row, 128-255 the J row.
    const int li   = tid & 127;
    const int inp  = tid >> 7;
    const float* src = inp ? Jp : Ip;
    const int lcol = li * 4;

    // Output ownership: 2 consecutive cols per thread.
    const int c0 = tid * 2;

    // Zero the pad wids (0 and 5) of edgebuf, both parities: 4 chunks of 60.
    {
        float* ez = &edgebuf[0][0][0][0][0];
        if (tid < 240) {
            int p = tid / 120, r = tid % 120;
            ez[p * 360 + (r < 60 ? r : 240 + r)] = 0.f;
        }
    }

    float v[5][2];
    #pragma unroll
    for (int q = 0; q < 5; ++q) { v[q][0] = 0.f; v[q][1] = 0.f; }

    float4 pend = make_float4(0.f, 0.f, 0.f, 0.f);
    {   // tick-0 load: row y0-4 (zero if above image)
        int r = y0 - 4;
        if (r >= 0) pend = *(const float4*)(src + r * W + lcol);
    }

    float cc_acc = 0.f;
    const float inv81 = 1.f / 81.f;

    // Ticks 1..25. Row k (global row y0-4+k): loaded at tick k, written at
    // k+1, v-added at k+2, v-subbed at k+11. Output i=t-10 for t=10..25.
    for (int t = 1; t <= 25; ++t) {
        // 1. write row loaded last tick into ring slot (t-1)%RS
        if (t <= 24) {
            int ws = (t - 1) % RS;
            *(float4*)&ring[ws][inp][lcol] = pend;
        }
        // 2. issue this tick's load (consumed next tick -> 1 tick of latency hiding)
        if (t <= 23) {
            int r = y0 - 4 + t;
            if (r >= 0 && r < H) pend = *(const float4*)(src + r * W + lcol);
            else                 pend = make_float4(0.f, 0.f, 0.f, 0.f);
        }
        // 3. vertical window updates (rows read from ring, written >=1 barrier ago)
        if (t >= 2) {               // add row k=t-2, slot (t-2)%RS
            int as = (t - 2) % RS;
            float2 ia = *(const float2*)&ring[as][0][c0];
            float2 ja = *(const float2*)&ring[as][1][c0];
            v[0][0] += ia.x;        v[0][1] += ia.y;
            v[1][0] += ja.x;        v[1][1] += ja.y;
            v[2][0] += ia.x * ia.x; v[2][1] += ia.y * ia.y;
            v[3][0] += ja.x * ja.x; v[3][1] += ja.y * ja.y;
            v[4][0] += ia.x * ja.x; v[4][1] += ia.y * ja.y;
        }
        if (t >= 11) {              // sub row k=t-11, slot t%RS (rewritten only at t+1: safe)
            int ss = t % RS;
            float2 is = *(const float2*)&ring[ss][0][c0];
            float2 js = *(const float2*)&ring[ss][1][c0];
            v[0][0] -= is.x;        v[0][1] -= is.y;
            v[1][0] -= js.x;        v[1][1] -= js.y;
            v[2][0] -= is.x * is.x; v[2][1] -= is.y * is.y;
            v[3][0] -= js.x * js.x; v[3][1] -= js.y * js.y;
            v[4][0] -= is.x * js.x; v[4][1] -= is.y * js.y;
        }
        float S[5];
        const int par = t & 1;
        if (t >= 10) {
            #pragma unroll
            for (int q = 0; q < 5; ++q) S[q] = v[q][0] + v[q][1];
            // publish wave-edge values for cross-wave horizontal halo
            int cls = lane == 0 ? 0 : lane == 1 ? 1 : lane == 62 ? 2 : lane == 63 ? 3 : -1;
            if (cls >= 0) {
                float* e = &edgebuf[par][wid + 1][cls][0][0];
                #pragma unroll
                for (int q = 0; q < 5; ++q) {
                    e[q * 3 + 0] = S[q];
                    e[q * 3 + 1] = v[q][0];
                    e[q * 3 + 2] = v[q][1];
                }
            }
        }
        __syncthreads();
        if (t >= 10) {
            // horizontal 9-sum for cols c0, c0+1 via shuffles + edge overrides
            const float* eL = &edgebuf[par][wid][0][0][0];
            const float* eR = &edgebuf[par][wid + 2][0][0][0];
            float h0[5], h1[5];
            #pragma unroll
            for (int q = 0; q < 5; ++q) {
                float Sm2  = __shfl_up(S[q], 2);
                float Sm1  = __shfl_up(S[q], 1);
                float v0m2 = __shfl_up(v[q][0], 2);
                float Sp1  = __shfl_down(S[q], 1);
                float v0p2 = __shfl_down(v[q][0], 2);
                float v1p2 = __shfl_down(v[q][1], 2);
                if (lane == 0)       { Sm2 = eL[30 + q*3]; v0m2 = eL[30 + q*3 + 1]; Sm1 = eL[45 + q*3]; }
                else if (lane == 1)  { Sm2 = eL[45 + q*3]; v0m2 = eL[45 + q*3 + 1]; }
                if (lane == 63)      { Sp1 = eR[q*3]; v0p2 = eR[15 + q*3 + 1]; v1p2 = eR[15 + q*3 + 2]; }
                else if (lane == 62) { v0p2 = eR[q*3 + 1]; v1p2 = eR[q*3 + 2]; }
                float t9 = ((Sm2 + Sm1) + (S[q] + Sp1)) + v0p2;  // [c0-4, c0+4]
                h0[q] = t9;
                h1[q] = (t9 - v0m2) + v1p2;                       // [c0-3, c0+5]
            }
            {
                float Is = h0[0], Js = h0[1];
                float u  = Is * inv81;
                float cr = h0[4] - u * Js;
                float Iv = h0[2] - u * Is;
                float Jv = h0[3] - (Js * inv81) * Js;
                cc_acc += cr * cr * __builtin_amdgcn_rcpf(Iv * Jv + 1e-6f);
            }
            {
                float Is = h1[0], Js = h1[1];
                float u  = Is * inv81;
                float cr = h1[4] - u * Js;
                float Iv = h1[2] - u * Is;
                float Jv = h1[3] - (Js * inv81) * Js;
                cc_acc += cr * cr * __builtin_amdgcn_rcpf(Iv * Jv + 1e-6f);
            }
        }
    }

    // Reduce: wave shuffle, then 4-wave combine.
    #pragma unroll
    for (int off = 32; off > 0; off >>= 1)
        cc_acc += __shfl_down(cc_acc, off, 64);
    if (lane == 0) wsum[wid] = cc_acc;
    __syncthreads();
    if (tid == 0)
        partials[blockIdx.x] = (wsum[0] + wsum[1]) + (wsum[2] + wsum[3]);
}

__global__ __launch_bounds__(256)
void ncc_finish(const float* __restrict__ partials, float* __restrict__ out,
                int n, float inv_total) {
    float v = 0.f;
    for (int i = threadIdx.x; i < n; i += blockDim.x) v += partials[i];
    #pragma unroll
    for (int off = 32; off > 0; off >>= 1)
        v += __shfl_down(v, off, 64);
    __shared__ float wsum[4];
    if ((threadIdx.x & 63) == 0) wsum[threadIdx.x >> 6] = v;
    __syncthreads();
    if (threadIdx.x == 0) {
        float t = (wsum[0] + wsum[1]) + (wsum[2] + wsum[3]);
        out[0] = 1.0f - t * inv_total;
    }
}

extern "C" void kernel_launch(void* const* d_in, const int* in_sizes, int n_in,
                              void* d_out, int out_size, void* d_ws, size_t ws_size,
                              hipStream_t stream) {
    const float* I = (const float*)d_in[0];   // predict
    const float* J = (const float*)d_in[1];   // target
    float* out = (float*)d_out;
    float* partials = (float*)d_ws;           // nblocks floats

    const int n = in_sizes[0];                // B*1*H*W
    const int B = n / (H * W);
    const int nblocks = B * NBANDS;           // 1024 for B=32

    ncc_main<<<nblocks, NT, 0, stream>>>(I, J, partials);
    ncc_finish<<<1, 256, 0, stream>>>(partials, out, nblocks, 1.0f / (float)n);
}